// Round 1
// baseline (142.750 us; speedup 1.0000x reference)
//
#include <hip/hip_runtime.h>
#include <hip/hip_bf16.h>

#define B_  512
#define T_  256
#define C_  384
#define H_  64
#define SCALE_ 0.05103103630798287f   // 384^-0.5

typedef float f32x4  __attribute__((ext_vector_type(4)));
typedef short bf16x8 __attribute__((ext_vector_type(8)));

__device__ __forceinline__ unsigned short f2bf(float f) {
    union { float f; unsigned u; } v; v.f = f;
    unsigned r = v.u + 0x7FFFu + ((v.u >> 16) & 1u);   // RNE
    return (unsigned short)(r >> 16);
}

// LDS layout (bytes), total 135168:
//  [0,      36864)  xs[256][72]  (phase-1 x staging)  | alias: Qs[256][72]
//  [36864,  64512)  wst[192][72] (phase-1 W^T staging)| alias: Pbuf[8][16*40]
//  [64512, 101376)  Ks[256][72]
//  [101376,135168)  Vt[64][264]
__global__ __launch_bounds__(512, 1) void att_head_kernel(
    const float* __restrict__ x,  const float* __restrict__ Wk,
    const float* __restrict__ Wq, const float* __restrict__ Wv,
    float* __restrict__ out)
{
    __shared__ __align__(16) char smem[135168];
    short* xs  = (short*)smem;              // ld 72
    short* wst = (short*)(smem + 36864);    // ld 72
    short* Qs  = (short*)smem;              // ld 72 (alias, written after xs dead)
    short* Pb  = (short*)(smem + 36864);    // 8 waves x [16][40]
    short* Ks  = (short*)(smem + 64512);    // ld 72
    short* Vt  = (short*)(smem + 101376);   // ld 264 (V transposed: Vt[h][t])

    const int tid  = threadIdx.x;
    const int b    = blockIdx.x;
    const int w    = tid >> 6;
    const int lane = tid & 63;
    const int g    = lane >> 4;
    const int i    = lane & 15;

    const float* xb = x + (size_t)b * T_ * C_;
    const float* Wm[3] = { Wk, Wq, Wv };

    f32x4 accP[2][12];
    #pragma unroll
    for (int s = 0; s < 2; s++)
        #pragma unroll
        for (int nb = 0; nb < 12; nb++)
            accP[s][nb] = f32x4{0.f, 0.f, 0.f, 0.f};

    const int rbA = 16 * w;
    const int rbB = 240 - 16 * w;

    // ---------------- Phase 1: QKV projection ----------------
    for (int kc = 0; kc < C_; kc += 64) {
        {   // stage x[b][:, kc:kc+64] -> xs as bf16 (float4 loads)
            const int c4 = tid & 15, tr = tid >> 4;
            #pragma unroll
            for (int p = 0; p < 8; p++) {
                const int t = p * 32 + tr;
                const float4 v = reinterpret_cast<const float4*>(xb + t * C_ + kc)[c4];
                unsigned u0 = ((unsigned)f2bf(v.y) << 16) | f2bf(v.x);
                unsigned u1 = ((unsigned)f2bf(v.w) << 16) | f2bf(v.z);
                unsigned* dst = (unsigned*)&xs[t * 72 + c4 * 4];
                dst[0] = u0; dst[1] = u1;
            }
        }
        {   // stage W chunk transposed: wst[m*64+n][k] = Wm[kc+k][n]
            const int n = tid & 63, kr = tid >> 6;
            #pragma unroll
            for (int m = 0; m < 3; m++) {
                const float* Wp = Wm[m];
                #pragma unroll
                for (int p = 0; p < 8; p++) {
                    const int k = p * 8 + kr;
                    wst[(m * 64 + n) * 72 + k] = (short)f2bf(Wp[(size_t)(kc + k) * H_ + n]);
                }
            }
        }
        __syncthreads();

        bf16x8 afs[2][2];
        #pragma unroll
        for (int s = 0; s < 2; s++) {
            const int rb = s ? rbB : rbA;
            #pragma unroll
            for (int ks = 0; ks < 2; ks++)
                afs[s][ks] = *(const bf16x8*)&xs[(rb + i) * 72 + ks * 32 + g * 8];
        }
        #pragma unroll
        for (int nb = 0; nb < 12; nb++) {
            #pragma unroll
            for (int ks = 0; ks < 2; ks++) {
                const bf16x8 bfr = *(const bf16x8*)&wst[(nb * 16 + i) * 72 + ks * 32 + g * 8];
                accP[0][nb] = __builtin_amdgcn_mfma_f32_16x16x32_bf16(afs[0][ks], bfr, accP[0][nb], 0, 0, 0);
                accP[1][nb] = __builtin_amdgcn_mfma_f32_16x16x32_bf16(afs[1][ks], bfr, accP[1][nb], 0, 0, 0);
            }
        }
        __syncthreads();   // protects staging rewrite; after last iter protects xs->Qs alias
    }

    // ---------------- Epilogue: scatter K,Q,V to LDS (bf16) ----------------
    #pragma unroll
    for (int s = 0; s < 2; s++) {
        const int rb = s ? rbB : rbA;
        #pragma unroll
        for (int nb = 0; nb < 12; nb++) {
            #pragma unroll
            for (int r = 0; r < 4; r++) {
                const int row = rb + 4 * g + r;
                const int col = nb * 16 + i;
                const short v = (short)f2bf(accP[s][nb][r]);
                if (nb < 4)      Ks[row * 72 + col]          = v;
                else if (nb < 8) Qs[row * 72 + (col - 64)]   = v;
                else             Vt[(col - 128) * 264 + row] = v;
            }
        }
    }
    __syncthreads();

    // ---------------- Phase 2: causal attention ----------------
    bf16x8 qf[2][2];
    #pragma unroll
    for (int s = 0; s < 2; s++) {
        const int rb = s ? rbB : rbA;
        #pragma unroll
        for (int ks = 0; ks < 2; ks++)
            qf[s][ks] = *(const bf16x8*)&Qs[(rb + i) * 72 + ks * 32 + g * 8];
    }
    short* myP = Pb + w * (16 * 40);
    const float NEG_INF = -__builtin_inff();

    #pragma unroll
    for (int s = 0; s < 2; s++) {
        const int rb  = s ? rbB : rbA;
        const int lim = s ? (15 - w) : w;   // max valid kv tile index (wave-uniform)

        f32x4 accS[16];
        #pragma unroll
        for (int nt = 0; nt < 16; nt++) accS[nt] = f32x4{0.f, 0.f, 0.f, 0.f};

        #pragma unroll
        for (int nt = 0; nt < 16; nt++) {
            if (nt <= lim) {
                #pragma unroll
                for (int ks = 0; ks < 2; ks++) {
                    const bf16x8 kf = *(const bf16x8*)&Ks[(nt * 16 + i) * 72 + ks * 32 + g * 8];
                    accS[nt] = __builtin_amdgcn_mfma_f32_16x16x32_bf16(qf[s][ks], kf, accS[nt], 0, 0, 0);
                }
            }
        }

        // scale + causal mask + row max
        float mrow[4] = { NEG_INF, NEG_INF, NEG_INF, NEG_INF };
        #pragma unroll
        for (int nt = 0; nt < 16; nt++) {
            #pragma unroll
            for (int r = 0; r < 4; r++) {
                const int col = nt * 16 + i;
                const int row = rb + 4 * g + r;
                float v = accS[nt][r] * SCALE_;
                v = (col <= row) ? v : NEG_INF;
                accS[nt][r] = v;
                mrow[r] = fmaxf(mrow[r], v);
            }
        }
        #pragma unroll
        for (int r = 0; r < 4; r++) {
            #pragma unroll
            for (int msk = 1; msk < 16; msk <<= 1)
                mrow[r] = fmaxf(mrow[r], __shfl_xor(mrow[r], msk, 64));
        }
        // exp + row sum
        float lsum[4] = { 0.f, 0.f, 0.f, 0.f };
        #pragma unroll
        for (int nt = 0; nt < 16; nt++) {
            #pragma unroll
            for (int r = 0; r < 4; r++) {
                const float p = __expf(accS[nt][r] - mrow[r]);   // exp(-inf)=0 on masked
                accS[nt][r] = p;
                lsum[r] += p;
            }
        }
        #pragma unroll
        for (int r = 0; r < 4; r++) {
            #pragma unroll
            for (int msk = 1; msk < 16; msk <<= 1)
                lsum[r] += __shfl_xor(lsum[r], msk, 64);
        }

        // P @ V over kv chunks of 32
        f32x4 accO[4];
        #pragma unroll
        for (int ht = 0; ht < 4; ht++) accO[ht] = f32x4{0.f, 0.f, 0.f, 0.f};

        #pragma unroll
        for (int ck = 0; ck < 8; ck++) {
            if (2 * ck <= lim) {
                #pragma unroll
                for (int t2 = 0; t2 < 2; t2++) {
                    const int nt = 2 * ck + t2;
                    #pragma unroll
                    for (int r = 0; r < 4; r++)
                        myP[(4 * g + r) * 40 + t2 * 16 + i] = (short)f2bf(accS[nt][r]);
                }
                asm volatile("s_waitcnt lgkmcnt(0)" ::: "memory");
                const bf16x8 pf = *(const bf16x8*)&myP[i * 40 + g * 8];
                #pragma unroll
                for (int ht = 0; ht < 4; ht++) {
                    const bf16x8 vf = *(const bf16x8*)&Vt[(ht * 16 + i) * 264 + ck * 32 + g * 8];
                    accO[ht] = __builtin_amdgcn_mfma_f32_16x16x32_bf16(pf, vf, accO[ht], 0, 0, 0);
                }
            }
        }

        // normalize + store
        float inv[4];
        #pragma unroll
        for (int r = 0; r < 4; r++) inv[r] = 1.f / lsum[r];
        #pragma unroll
        for (int ht = 0; ht < 4; ht++) {
            #pragma unroll
            for (int r = 0; r < 4; r++) {
                const int row = rb + 4 * g + r;
                out[((size_t)b * T_ + row) * H_ + ht * 16 + i] = accO[ht][r] * inv[r];
            }
        }
    }
}

extern "C" void kernel_launch(void* const* d_in, const int* in_sizes, int n_in,
                              void* d_out, int out_size, void* d_ws, size_t ws_size,
                              hipStream_t stream) {
    const float* x  = (const float*)d_in[0];
    const float* Wk = (const float*)d_in[1];
    const float* Wq = (const float*)d_in[2];
    const float* Wv = (const float*)d_in[3];
    float* out = (float*)d_out;
    (void)d_ws; (void)ws_size; (void)in_sizes; (void)n_in; (void)out_size;
    att_head_kernel<<<dim3(B_), dim3(512), 0, stream>>>(x, Wk, Wq, Wv, out);
}

// Round 2
// 104.258 us; speedup vs baseline: 1.3692x; 1.3692x over previous
//
#include <hip/hip_runtime.h>
#include <hip/hip_bf16.h>

#define B_  512
#define T_  256
#define C_  384
#define H_  64
#define SCALE_ 0.05103103630798287f   // 384^-0.5

typedef float f32x4  __attribute__((ext_vector_type(4)));
typedef short bf16x8 __attribute__((ext_vector_type(8)));

__device__ __forceinline__ unsigned short f2bf(float f) {
    union { float f; unsigned u; } v; v.f = f;
    unsigned r = v.u + 0x7FFFu + ((v.u >> 16) & 1u);   // RNE
    return (unsigned short)(r >> 16);
}

// LDS layout (bytes), total 135168:
//  [0,      36864)  xs[256][72]  (phase-1 x staging)  | alias: Qs[256][72]
//  [36864,  64512)  wst[192][72] (phase-1 W^T staging)| alias: Pbuf[16][16*40] (20480 B used)
//  [64512, 101376)  Ks[256][72]
//  [101376,135168)  Vt[64][264]
//
// 1024 threads = 16 waves; wave w owns Q-row strip [16w, 16w+16).
// LDS 132 KB -> 1 WG/CU, 16 waves/CU = 4 waves/SIMD (needs VGPR<=128).
__global__ __launch_bounds__(1024, 1) void att_head_kernel(
    const float* __restrict__ x,  const float* __restrict__ Wk,
    const float* __restrict__ Wq, const float* __restrict__ Wv,
    float* __restrict__ out)
{
    __shared__ __align__(16) char smem[135168];
    short* xs  = (short*)smem;              // ld 72
    short* wst = (short*)(smem + 36864);    // ld 72
    short* Qs  = (short*)smem;              // ld 72 (alias, written after xs dead)
    short* Pb  = (short*)(smem + 36864);    // 16 waves x [16][40]
    short* Ks  = (short*)(smem + 64512);    // ld 72
    short* Vt  = (short*)(smem + 101376);   // ld 264 (V transposed: Vt[h][t])

    const int tid  = threadIdx.x;
    const int b    = blockIdx.x;
    const int w    = tid >> 6;        // 0..15
    const int lane = tid & 63;
    const int g    = lane >> 4;
    const int i    = lane & 15;
    const int rb   = 16 * w;          // this wave's Q-row strip base

    const float* xb = x + (size_t)b * T_ * C_;
    const float* Wm[3] = { Wk, Wq, Wv };

    f32x4 accP[12];
    #pragma unroll
    for (int nb = 0; nb < 12; nb++)
        accP[nb] = f32x4{0.f, 0.f, 0.f, 0.f};

    // ---------------- Phase 1: QKV projection ----------------
    for (int kc = 0; kc < C_; kc += 64) {
        {   // stage x[b][:, kc:kc+64] -> xs as bf16 (float4 loads)
            const int c4 = tid & 15, tr = tid >> 4;   // tr: 0..63
            #pragma unroll
            for (int p = 0; p < 4; p++) {
                const int t = p * 64 + tr;
                const float4 v = reinterpret_cast<const float4*>(xb + t * C_ + kc)[c4];
                unsigned u0 = ((unsigned)f2bf(v.y) << 16) | f2bf(v.x);
                unsigned u1 = ((unsigned)f2bf(v.w) << 16) | f2bf(v.z);
                unsigned* dst = (unsigned*)&xs[t * 72 + c4 * 4];
                dst[0] = u0; dst[1] = u1;
            }
        }
        {   // stage W chunk transposed: wst[m*64+n][k] = Wm[kc+k][n]
            const int n = tid & 63, kr = tid >> 6;    // kr: 0..15
            #pragma unroll
            for (int m = 0; m < 3; m++) {
                const float* Wp = Wm[m];
                #pragma unroll
                for (int p = 0; p < 4; p++) {
                    const int k = p * 16 + kr;
                    wst[(m * 64 + n) * 72 + k] = (short)f2bf(Wp[(size_t)(kc + k) * H_ + n]);
                }
            }
        }
        __syncthreads();

        bf16x8 afs[2];
        #pragma unroll
        for (int ks = 0; ks < 2; ks++)
            afs[ks] = *(const bf16x8*)&xs[(rb + i) * 72 + ks * 32 + g * 8];

        #pragma unroll
        for (int nb = 0; nb < 12; nb++) {
            #pragma unroll
            for (int ks = 0; ks < 2; ks++) {
                const bf16x8 bfr = *(const bf16x8*)&wst[(nb * 16 + i) * 72 + ks * 32 + g * 8];
                accP[nb] = __builtin_amdgcn_mfma_f32_16x16x32_bf16(afs[ks], bfr, accP[nb], 0, 0, 0);
            }
        }
        __syncthreads();   // protects staging rewrite; after last iter protects xs->Qs alias
    }

    // ---------------- Epilogue: scatter K,Q,V to LDS (bf16) ----------------
    #pragma unroll
    for (int nb = 0; nb < 12; nb++) {
        #pragma unroll
        for (int r = 0; r < 4; r++) {
            const int row = rb + 4 * g + r;
            const int col = nb * 16 + i;
            const short v = (short)f2bf(accP[nb][r]);
            if (nb < 4)      Ks[row * 72 + col]          = v;
            else if (nb < 8) Qs[row * 72 + (col - 64)]   = v;
            else             Vt[(col - 128) * 264 + row] = v;
        }
    }
    __syncthreads();

    // ---------------- Phase 2: causal attention ----------------
    bf16x8 qf[2];
    #pragma unroll
    for (int ks = 0; ks < 2; ks++)
        qf[ks] = *(const bf16x8*)&Qs[(rb + i) * 72 + ks * 32 + g * 8];

    short* myP = Pb + w * (16 * 40);
    const float NEG_INF = -__builtin_inff();
    const int lim = w;   // max valid kv tile index (wave-uniform)

    f32x4 accS[16];
    #pragma unroll
    for (int nt = 0; nt < 16; nt++) accS[nt] = f32x4{0.f, 0.f, 0.f, 0.f};

    #pragma unroll
    for (int nt = 0; nt < 16; nt++) {
        if (nt <= lim) {
            #pragma unroll
            for (int ks = 0; ks < 2; ks++) {
                const bf16x8 kf = *(const bf16x8*)&Ks[(nt * 16 + i) * 72 + ks * 32 + g * 8];
                accS[nt] = __builtin_amdgcn_mfma_f32_16x16x32_bf16(qf[ks], kf, accS[nt], 0, 0, 0);
            }
        }
    }

    // scale + causal mask + row max
    float mrow[4] = { NEG_INF, NEG_INF, NEG_INF, NEG_INF };
    #pragma unroll
    for (int nt = 0; nt < 16; nt++) {
        #pragma unroll
        for (int r = 0; r < 4; r++) {
            const int col = nt * 16 + i;
            const int row = rb + 4 * g + r;
            float v = accS[nt][r] * SCALE_;
            v = (col <= row) ? v : NEG_INF;
            accS[nt][r] = v;
            mrow[r] = fmaxf(mrow[r], v);
        }
    }
    #pragma unroll
    for (int r = 0; r < 4; r++) {
        #pragma unroll
        for (int msk = 1; msk < 16; msk <<= 1)
            mrow[r] = fmaxf(mrow[r], __shfl_xor(mrow[r], msk, 64));
    }
    // exp + row sum
    float lsum[4] = { 0.f, 0.f, 0.f, 0.f };
    #pragma unroll
    for (int nt = 0; nt < 16; nt++) {
        #pragma unroll
        for (int r = 0; r < 4; r++) {
            const float p = __expf(accS[nt][r] - mrow[r]);   // exp(-inf)=0 on masked
            accS[nt][r] = p;
            lsum[r] += p;
        }
    }
    #pragma unroll
    for (int r = 0; r < 4; r++) {
        #pragma unroll
        for (int msk = 1; msk < 16; msk <<= 1)
            lsum[r] += __shfl_xor(lsum[r], msk, 64);
    }

    // P @ V over kv chunks of 32
    f32x4 accO[4];
    #pragma unroll
    for (int ht = 0; ht < 4; ht++) accO[ht] = f32x4{0.f, 0.f, 0.f, 0.f};

    #pragma unroll
    for (int ck = 0; ck < 8; ck++) {
        if (2 * ck <= lim) {
            #pragma unroll
            for (int t2 = 0; t2 < 2; t2++) {
                const int nt = 2 * ck + t2;
                #pragma unroll
                for (int r = 0; r < 4; r++)
                    myP[(4 * g + r) * 40 + t2 * 16 + i] = (short)f2bf(accS[nt][r]);
            }
            asm volatile("s_waitcnt lgkmcnt(0)" ::: "memory");
            const bf16x8 pf = *(const bf16x8*)&myP[i * 40 + g * 8];
            #pragma unroll
            for (int ht = 0; ht < 4; ht++) {
                const bf16x8 vf = *(const bf16x8*)&Vt[(ht * 16 + i) * 264 + ck * 32 + g * 8];
                accO[ht] = __builtin_amdgcn_mfma_f32_16x16x32_bf16(pf, vf, accO[ht], 0, 0, 0);
            }
        }
    }

    // normalize + store
    float inv[4];
    #pragma unroll
    for (int r = 0; r < 4; r++) inv[r] = 1.f / lsum[r];
    #pragma unroll
    for (int ht = 0; ht < 4; ht++) {
        #pragma unroll
        for (int r = 0; r < 4; r++) {
            const int row = rb + 4 * g + r;
            out[((size_t)b * T_ + row) * H_ + ht * 16 + i] = accO[ht][r] * inv[r];
        }
    }
}

extern "C" void kernel_launch(void* const* d_in, const int* in_sizes, int n_in,
                              void* d_out, int out_size, void* d_ws, size_t ws_size,
                              hipStream_t stream) {
    const float* x  = (const float*)d_in[0];
    const float* Wk = (const float*)d_in[1];
    const float* Wq = (const float*)d_in[2];
    const float* Wv = (const float*)d_in[3];
    float* out = (float*)d_out;
    (void)d_ws; (void)ws_size; (void)in_sizes; (void)n_in; (void)out_size;
    att_head_kernel<<<dim3(B_), dim3(1024), 0, stream>>>(x, Wk, Wq, Wv, out);
}

// Round 3
// 60.216 us; speedup vs baseline: 2.3706x; 1.7314x over previous
//
#include <hip/hip_runtime.h>
#include <hip/hip_bf16.h>

#define B_  512
#define T_  256
#define C_  384
#define H_  64
#define SCALE_ 0.05103103630798287f   // 384^-0.5

typedef float f32x4  __attribute__((ext_vector_type(4)));
typedef short bf16x8 __attribute__((ext_vector_type(8)));
typedef short bf16x4 __attribute__((ext_vector_type(4)));

__device__ __forceinline__ unsigned short f2bf(float f) {
    union { float f; unsigned u; } v; v.f = f;
    unsigned r = v.u + 0x7FFFu + ((v.u >> 16) & 1u);   // RNE
    return (unsigned short)(r >> 16);
}

// Element index into an XOR-swizzled [R][64]-short tile (row = 128 B = 8 x 16B blocks).
// blk' = blk ^ (row&7) -> a wave's b128 reads at rows i=0..15 spread across all banks (2-way, free).
__device__ __forceinline__ int swz64(int row, int col) {
    return row * 64 + (((col >> 3) ^ (row & 7)) << 3) + (col & 7);
}

// LDS layout (shorts), total 67584 shorts = 135168 B:
//  [0,     24576)  wst[2][192*64]  W^T double buffer   | alias after phase1: Qs[256][64] swz
//  [24576, 34816)  Pb: 16 waves x [16][40] swizzled P scratch
//  [34816, 51200)  Ks[256][64] swz
//  [51200, 67584)  Vt[64][256]->[64 rows h][256 t] swz ([R][64]-style per 64-col... stored as [64][256]? no:
//                  Vt is [64][256] t-major: rows h (64), cols t (256): swizzle per 64-col groups not needed —
//                  we store as [64][256] with blk' = (t>>3)^(h&7) within each row (row = 512B = 32 blocks,
//                  XOR only affects low 3 block bits).
__global__ __launch_bounds__(1024, 4) void att_head_kernel(
    const float* __restrict__ x,  const float* __restrict__ Wk,
    const float* __restrict__ Wq, const float* __restrict__ Wv,
    float* __restrict__ out)
{
    __shared__ __align__(16) short smem[67584];
    short* const wst0 = smem;
    short* const wst1 = smem + 12288;
    short* const Qs   = smem;                // alias (written after wst dead)
    short* const Pb   = smem + 24576;
    short* const Ks   = smem + 34816;
    short* const Vt   = smem + 51200;

    const int tid  = threadIdx.x;
    const int b    = blockIdx.x;
    const int w    = tid >> 6;        // 0..15  (also the W-stage k-quad index)
    const int lane = tid & 63;
    const int g    = lane >> 4;
    const int i    = lane & 15;
    const int rb   = 16 * w;

    const float* xb = x + (size_t)b * T_ * C_;
    const float* Wm[3] = { Wk, Wq, Wv };

    f32x4 accP[12];
    #pragma unroll
    for (int nb = 0; nb < 12; nb++) accP[nb] = f32x4{0.f, 0.f, 0.f, 0.f};

    // per-lane global base for this wave's A-rows
    const float* xrow = xb + (size_t)(rb + i) * C_ + g * 8;

    // ---- W staging: thread (w, lane): rows m*64+lane, k-quad w -> packed b64, swizzled ----
    auto stageW = [&](int kc, short* buf) {
        #pragma unroll
        for (int m = 0; m < 3; m++) {
            const float* Wp = Wm[m] + (size_t)(kc + w * 4) * H_ + lane;
            bf16x4 pk;
            #pragma unroll
            for (int jj = 0; jj < 4; jj++) pk[jj] = (short)f2bf(Wp[jj * H_]);
            const int row = m * 64 + lane;
            const int k0  = w * 4;
            *(bf16x4*)&buf[row * 64 + (((k0 >> 3) ^ (row & 7)) << 3) + (k0 & 7)] = pk;
        }
    };

    // ---------------- Phase 1: QKV projection (db W in LDS, x direct to regs) ------------
    float4 xr[2][4];   // [parity][ks*2+half]
    #pragma unroll
    for (int ks = 0; ks < 2; ks++)
        #pragma unroll
        for (int h = 0; h < 2; h++)
            xr[0][ks * 2 + h] = *(const float4*)(xrow + ks * 32 + h * 4);
    stageW(0, wst0);
    asm volatile("s_waitcnt lgkmcnt(0)\n\ts_barrier" ::: "memory");

    #pragma unroll
    for (int j = 0; j < 6; j++) {
        const int par = j & 1;
        short* cur = par ? wst1 : wst0;
        if (j < 5) {   // prefetch next chunk: x -> regs, W -> other LDS buffer
            #pragma unroll
            for (int ks = 0; ks < 2; ks++)
                #pragma unroll
                for (int h = 0; h < 2; h++)
                    xr[par ^ 1][ks * 2 + h] = *(const float4*)(xrow + (j + 1) * 64 + ks * 32 + h * 4);
            stageW((j + 1) * 64, par ? wst0 : wst1);
        }
        bf16x8 afs[2];
        #pragma unroll
        for (int ks = 0; ks < 2; ks++)
            #pragma unroll
            for (int h = 0; h < 2; h++) {
                const float4 v = xr[par][ks * 2 + h];
                afs[ks][h * 4 + 0] = (short)f2bf(v.x);
                afs[ks][h * 4 + 1] = (short)f2bf(v.y);
                afs[ks][h * 4 + 2] = (short)f2bf(v.z);
                afs[ks][h * 4 + 3] = (short)f2bf(v.w);
            }
        #pragma unroll
        for (int nb = 0; nb < 12; nb++)
            #pragma unroll
            for (int ks = 0; ks < 2; ks++) {
                const int brow = nb * 16 + i;
                const bf16x8 bfr = *(const bf16x8*)&cur[brow * 64 + (((ks * 4 + g) ^ (i & 7)) << 3)];
                accP[nb] = __builtin_amdgcn_mfma_f32_16x16x32_bf16(afs[ks], bfr, accP[nb], 0, 0, 0);
            }
        asm volatile("s_waitcnt lgkmcnt(0)\n\ts_barrier" ::: "memory");
    }

    // ---------------- Epilogue: scatter K,Q (b16) and V (packed b64) to swizzled LDS -----
    #pragma unroll
    for (int nb = 0; nb < 4; nb++)
        #pragma unroll
        for (int r = 0; r < 4; r++)
            Ks[swz64(rb + 4 * g + r, nb * 16 + i)] = (short)f2bf(accP[nb][r]);
    #pragma unroll
    for (int nb = 0; nb < 4; nb++)
        #pragma unroll
        for (int r = 0; r < 4; r++)
            Qs[swz64(rb + 4 * g + r, nb * 16 + i)] = (short)f2bf(accP[4 + nb][r]);
    #pragma unroll
    for (int nb = 0; nb < 4; nb++) {
        const int hrow = nb * 16 + i;
        const int t0   = rb + 4 * g;
        bf16x4 pk;
        #pragma unroll
        for (int r = 0; r < 4; r++) pk[r] = (short)f2bf(accP[8 + nb][r]);
        // Vt row = 256 shorts = 512B; swizzle low 3 bits of 16B-block index
        const int blk = t0 >> 3;
        *(bf16x4*)&Vt[hrow * 256 + (((blk & ~7) | ((blk ^ (hrow & 7)) & 7)) << 3) + (t0 & 7)] = pk;
    }
    asm volatile("s_waitcnt lgkmcnt(0)\n\ts_barrier" ::: "memory");

    // ---------------- Phase 2: causal attention ----------------
    bf16x8 qf[2];
    #pragma unroll
    for (int ks = 0; ks < 2; ks++)
        qf[ks] = *(const bf16x8*)&Qs[(rb + i) * 64 + (((ks * 4 + g) ^ (i & 7)) << 3)];

    short* myP = Pb + w * 640;                 // [16][40] shorts, block-swizzled
    const float NEG_INF = -__builtin_inff();
    const int lim = w;

    f32x4 accS[16];
    #pragma unroll
    for (int nt = 0; nt < 16; nt++) accS[nt] = f32x4{0.f, 0.f, 0.f, 0.f};

    #pragma unroll
    for (int nt = 0; nt < 16; nt++) {
        if (nt <= lim) {
            #pragma unroll
            for (int ks = 0; ks < 2; ks++) {
                const bf16x8 kf = *(const bf16x8*)&Ks[(nt * 16 + i) * 64 + (((ks * 4 + g) ^ (i & 7)) << 3)];
                accS[nt] = __builtin_amdgcn_mfma_f32_16x16x32_bf16(qf[ks], kf, accS[nt], 0, 0, 0);
            }
        }
    }

    float mrow[4] = { NEG_INF, NEG_INF, NEG_INF, NEG_INF };
    #pragma unroll
    for (int nt = 0; nt < 16; nt++)
        #pragma unroll
        for (int r = 0; r < 4; r++) {
            const int col = nt * 16 + i;
            const int row = rb + 4 * g + r;
            float v = accS[nt][r] * SCALE_;
            v = (col <= row) ? v : NEG_INF;
            accS[nt][r] = v;
            mrow[r] = fmaxf(mrow[r], v);
        }
    #pragma unroll
    for (int r = 0; r < 4; r++)
        #pragma unroll
        for (int msk = 1; msk < 16; msk <<= 1)
            mrow[r] = fmaxf(mrow[r], __shfl_xor(mrow[r], msk, 64));

    float lsum[4] = { 0.f, 0.f, 0.f, 0.f };
    #pragma unroll
    for (int nt = 0; nt < 16; nt++)
        #pragma unroll
        for (int r = 0; r < 4; r++) {
            const float p = __expf(accS[nt][r] - mrow[r]);
            accS[nt][r] = p;
            lsum[r] += p;
        }
    #pragma unroll
    for (int r = 0; r < 4; r++)
        #pragma unroll
        for (int msk = 1; msk < 16; msk <<= 1)
            lsum[r] += __shfl_xor(lsum[r], msk, 64);

    f32x4 accO[4];
    #pragma unroll
    for (int ht = 0; ht < 4; ht++) accO[ht] = f32x4{0.f, 0.f, 0.f, 0.f};

    #pragma unroll
    for (int ck = 0; ck < 8; ck++) {
        if (2 * ck <= lim) {
            #pragma unroll
            for (int t2 = 0; t2 < 2; t2++)
                #pragma unroll
                for (int r = 0; r < 4; r++) {
                    const int q = 4 * g + r, kk = t2 * 16 + i;
                    myP[q * 40 + ((((kk >> 3) ^ (q >> 2)) & 3) << 3) + (kk & 7)] =
                        (short)f2bf(accS[2 * ck + t2][r]);
                }
            asm volatile("s_waitcnt lgkmcnt(0)" ::: "memory");
            const bf16x8 pf = *(const bf16x8*)&myP[i * 40 + (((g ^ (i >> 2)) & 3) << 3)];
            #pragma unroll
            for (int ht = 0; ht < 4; ht++) {
                const int hrow = ht * 16 + i;
                const int blk  = ck * 4 + g;
                const bf16x8 vf = *(const bf16x8*)&Vt[hrow * 256 +
                        (((blk & ~7) | ((blk ^ (hrow & 7)) & 7)) << 3)];
                accO[ht] = __builtin_amdgcn_mfma_f32_16x16x32_bf16(pf, vf, accO[ht], 0, 0, 0);
            }
        }
    }

    float inv[4];
    #pragma unroll
    for (int r = 0; r < 4; r++) inv[r] = 1.f / lsum[r];
    #pragma unroll
    for (int ht = 0; ht < 4; ht++)
        #pragma unroll
        for (int r = 0; r < 4; r++) {
            const int row = rb + 4 * g + r;
            out[((size_t)b * T_ + row) * H_ + ht * 16 + i] = accO[ht][r] * inv[r];
        }
}

extern "C" void kernel_launch(void* const* d_in, const int* in_sizes, int n_in,
                              void* d_out, int out_size, void* d_ws, size_t ws_size,
                              hipStream_t stream) {
    const float* x  = (const float*)d_in[0];
    const float* Wk = (const float*)d_in[1];
    const float* Wq = (const float*)d_in[2];
    const float* Wv = (const float*)d_in[3];
    float* out = (float*)d_out;
    (void)d_ws; (void)ws_size; (void)in_sizes; (void)n_in; (void)out_size;
    att_head_kernel<<<dim3(B_), dim3(1024), 0, stream>>>(x, Wk, Wq, Wv, out);
}